// Round 7
// baseline (198.566 us; speedup 1.0000x reference)
//
#include <hip/hip_runtime.h>
#include <math.h>

// Problem constants: B=16, C_in=256, H=W=32 -> N=1024, qkv_out=1536,
// HEAD=8, dh=dv=64, V_DIM=512, OUT_CH=256.
static constexpr int Bsz = 16;
static constexpr int Np  = 1024;
static constexpr int Cin = 256;

typedef __attribute__((ext_vector_type(8))) short short8;  // 8 bf16 = 4 VGPR
typedef __attribute__((ext_vector_type(4))) float f4;      // mfma acc

// v_exp_f32 computes 2^x natively.
#if defined(__has_builtin)
#if __has_builtin(__builtin_amdgcn_exp2f)
#define EXP2(x) __builtin_amdgcn_exp2f(x)
#else
#define EXP2(x) exp2f(x)
#endif
#else
#define EXP2(x) exp2f(x)
#endif

// q pre-scale: dh^-0.5 * log2(e) (scores exit QK^T in log2 domain)
#define QSCALE 0.18033688011112f

// fp32 -> bf16 round-to-nearest-even
__device__ __forceinline__ unsigned short f2b(float f) {
    union { float fp; unsigned int u; } v; v.fp = f;
    unsigned int r = v.u + 0x7fffu + ((v.u >> 16) & 1u);
    return (unsigned short)(r >> 16);
}

// ---------------------------------------------------------------------------
// Kernel 0: cast+transpose x [b][c][n] fp32 -> xb [b][n][c] bf16 (y<4),
// and cast qkv_w / proj_w fp32 -> bf16 (y==4). Single launch.
// ---------------------------------------------------------------------------
__global__ __launch_bounds__(256)
void cast_xw(const float* __restrict__ x, const float* __restrict__ qw,
             const float* __restrict__ pw, ushort* __restrict__ xb,
             ushort* __restrict__ qwb, ushort* __restrict__ pwb)
{
    const int t = threadIdx.x;
    if (blockIdx.y < 4) {
        __shared__ ushort T[64][72];   // [n][c]
        const int n0 = blockIdx.x * 64, c0 = blockIdx.y * 64, b = blockIdx.z;
        {   // read 64c x 64n, convert, transposed scatter into LDS
            const int c_l = t >> 2, ns = (t & 3) * 16;
            const float* src = &x[((b * Cin + c0 + c_l) << 10) + n0 + ns];
#pragma unroll
            for (int i = 0; i < 4; ++i) {
                const float4 v = *(const float4*)(src + 4 * i);
                T[ns + 4 * i + 0][c_l] = f2b(v.x);
                T[ns + 4 * i + 1][c_l] = f2b(v.y);
                T[ns + 4 * i + 2][c_l] = f2b(v.z);
                T[ns + 4 * i + 3][c_l] = f2b(v.w);
            }
        }
        __syncthreads();
        {   // write rows of c (contiguous) to xb
            const int n_l = t >> 2, cs = (t & 3) * 16;
            ushort* dst = &xb[((b << 10) + n0 + n_l) * Cin + c0 + cs];
            *(uint4*)dst       = *(const uint4*)&T[n_l][cs];
            *(uint4*)(dst + 8) = *(const uint4*)&T[n_l][cs + 8];
        }
    } else {
        // weights: 524288 floats = 131072 float4; 256 blocks x 256 thr x 2
        const int nq4 = (1536 * Cin) / 4;
        const int base = ((blockIdx.z * 16 + blockIdx.x) * 256 + t) * 2;
#pragma unroll
        for (int g = 0; g < 2; ++g) {
            const int j = base + g;
            const float* src; ushort* dst; int jj;
            if (j < nq4) { src = qw; dst = qwb; jj = j; }
            else         { src = pw; dst = pwb; jj = j - nq4; }
            const float4 v = *(const float4*)(src + 4 * jj);
            ushort4 u; u.x = f2b(v.x); u.y = f2b(v.y); u.z = f2b(v.z); u.w = f2b(v.w);
            *(ushort4*)(dst + 4 * jj) = u;
        }
    }
}

// ---------------------------------------------------------------------------
// Kernel 1: QKV GEMM, bf16 MFMA 16x16x32, BK=64.
// Q/K o-tiles: C = W*X -> Ct [n][o] -> q/k [bh][n][64] (q pre-scaled QSCALE).
// V  o-tiles: swapped operands (C^T = X*W) -> vbuf TRANSPOSED [bh][d][n].
// ---------------------------------------------------------------------------
__global__ __launch_bounds__(256)
void qkv_gemm(const ushort* __restrict__ xb, const ushort* __restrict__ wb,
              const float* __restrict__ bias,
              ushort* __restrict__ qb, ushort* __restrict__ kb, ushort* __restrict__ vb)
{
    __shared__ ushort lds[18432];        // 36.9 KB; staging + epilogue alias
    ushort* As = lds;                    // [128 o][72]
    ushort* Bs = lds + 9216;             // [128 n][72]

    const int t = threadIdx.x;
    const int w = t >> 6, lane = t & 63, quad = lane >> 4, ln = lane & 15;
    const int n0 = blockIdx.x * 128;
    const int o0 = blockIdx.y * 128;
    const int b  = blockIdx.z;
    const int ow = (w & 1) * 64, nw = (w >> 1) * 64;
    const bool vpath = (o0 >= 1024);

    f4 acc[4][4];
#pragma unroll
    for (int i = 0; i < 4; ++i)
#pragma unroll
        for (int j = 0; j < 4; ++j) acc[i][j] = (f4){0.f, 0.f, 0.f, 0.f};

    const int rr = t >> 2, cc = (t & 3) * 16;
    for (int k0 = 0; k0 < Cin; k0 += 64) {
        __syncthreads();
#pragma unroll
        for (int p = 0; p < 2; ++p) {   // stage 128 rows x 64 k for A and B
            const int row = rr + p * 64;
            const ushort* sa = &wb[(o0 + row) * Cin + k0 + cc];
            *(uint4*)&As[row * 72 + cc]     = *(const uint4*)sa;
            *(uint4*)&As[row * 72 + cc + 8] = *(const uint4*)(sa + 8);
            const ushort* sb = &xb[((b << 10) + n0 + row) * Cin + k0 + cc];
            *(uint4*)&Bs[row * 72 + cc]     = *(const uint4*)sb;
            *(uint4*)&Bs[row * 72 + cc + 8] = *(const uint4*)(sb + 8);
        }
        __syncthreads();
#pragma unroll
        for (int sub = 0; sub < 2; ++sub) {
            short8 af[4], bf[4];
#pragma unroll
            for (int ot = 0; ot < 4; ++ot)
                af[ot] = *(const short8*)&As[(ow + ot * 16 + ln) * 72 + sub * 32 + quad * 8];
#pragma unroll
            for (int nt = 0; nt < 4; ++nt)
                bf[nt] = *(const short8*)&Bs[(nw + nt * 16 + ln) * 72 + sub * 32 + quad * 8];
            if (!vpath) {   // acc[ot][nt]: row = o, col = n
#pragma unroll
                for (int ot = 0; ot < 4; ++ot)
#pragma unroll
                    for (int nt = 0; nt < 4; ++nt)
                        acc[ot][nt] = __builtin_amdgcn_mfma_f32_16x16x32_bf16(
                            af[ot], bf[nt], acc[ot][nt], 0, 0, 0);
            } else {        // acc[nt][ot]: row = n, col = o (transposed C)
#pragma unroll
                for (int nt = 0; nt < 4; ++nt)
#pragma unroll
                    for (int ot = 0; ot < 4; ++ot)
                        acc[nt][ot] = __builtin_amdgcn_mfma_f32_16x16x32_bf16(
                            bf[nt], af[ot], acc[nt][ot], 0, 0, 0);
            }
        }
    }

    __syncthreads();                     // staging reads done; alias lds
    if (!vpath) {
        // ---- Q/K epilogue: Ct [n][136 o-stride] ----
        ushort* Ct = lds;
        const float sc = (o0 < 512) ? QSCALE : 1.0f;
#pragma unroll
        for (int ot = 0; ot < 4; ++ot) {
            float bs[4];
#pragma unroll
            for (int rg = 0; rg < 4; ++rg)
                bs[rg] = bias[o0 + ow + ot * 16 + quad * 4 + rg];
#pragma unroll
            for (int nt = 0; nt < 4; ++nt) {
                ushort4 u;
                u.x = f2b((acc[ot][nt][0] + bs[0]) * sc);
                u.y = f2b((acc[ot][nt][1] + bs[1]) * sc);
                u.z = f2b((acc[ot][nt][2] + bs[2]) * sc);
                u.w = f2b((acc[ot][nt][3] + bs[3]) * sc);
                *(ushort4*)&Ct[(nw + nt * 16 + ln) * 136 + ow + ot * 16 + quad * 4] = u;
            }
        }
        __syncthreads();
        ushort* dst; int obase;
        if (o0 < 512) { dst = qb; obase = o0; }
        else          { dst = kb; obase = o0 - 512; }
        const int rn = t >> 1, hf = t & 1;
        const int bh = b * 8 + (obase >> 6) + hf;
        ushort* drow = &dst[(bh * Np + n0 + rn) << 6];
        const ushort* srow = &Ct[rn * 136 + hf * 64];
#pragma unroll
        for (int s = 0; s < 8; ++s)
            *(uint4*)(drow + s * 8) = *(const uint4*)(srow + s * 8);
    } else {
        // ---- V epilogue: Ct [o][136 n-stride] (rows = d), then [bh][d][n] ----
        ushort* Ct = lds;
#pragma unroll
        for (int ot = 0; ot < 4; ++ot) {
            const float bo = bias[o0 + ow + ot * 16 + ln];
#pragma unroll
            for (int nt = 0; nt < 4; ++nt) {
                ushort4 u;
                u.x = f2b(acc[nt][ot][0] + bo);
                u.y = f2b(acc[nt][ot][1] + bo);
                u.z = f2b(acc[nt][ot][2] + bo);
                u.w = f2b(acc[nt][ot][3] + bo);
                *(ushort4*)&Ct[(ow + ot * 16 + ln) * 136 + nw + nt * 16 + quad * 4] = u;
            }
        }
        __syncthreads();
        const int o_l = t >> 1, nh = (t & 1) * 64;
        const int bh = b * 8 + ((o0 - 1024) >> 6) + (o_l >> 6);
        ushort* drow = &vb[((size_t)bh << 16) + ((o_l & 63) << 10) + n0 + nh];
        const ushort* srow = &Ct[o_l * 136 + nh];
#pragma unroll
        for (int s = 0; s < 8; ++s)
            *(uint4*)(drow + s * 8) = *(const uint4*)(srow + s * 8);
    }
}

// ---------------------------------------------------------------------------
// Kernel 2: BARRIER-FREE causal flash attention. Zero __syncthreads.
// Each wave owns 32 q-rows (2 strips of 16); K/V/Q MFMA fragments load
// DIRECTLY from global (L1/L2-resident), shared by both strips. Accumulates
// O^T = V^T * P^T (A/B frag layouts are identical -> operand swap free):
// output cols = q = lane, so alpha-rescale is per-lane (no shuffles).
// LDS: only the wave-private P round-trip (C/D -> B-operand layout).
// Softmax in log2 domain (q pre-scaled by dh^-0.5*log2e in qkv).
// ---------------------------------------------------------------------------
__global__ __launch_bounds__(256)
void attn(const ushort* __restrict__ qb, const ushort* __restrict__ kb,
          const ushort* __restrict__ vt, ushort* __restrict__ ob)
{
    __shared__ ushort Ps[128 * 72];   // 18.4 KB; rows w*32 .. w*32+31 per wave

    const int t = threadIdx.x;
    const int w = t >> 6, lane = t & 63, quad = lane >> 4, ln = lane & 15;
    const int bh = blockIdx.x & 127;
    const int qp = 7 - (blockIdx.x >> 7);      // heavy q-blocks first
    const int jj = qp * 4 + w;                 // 32-row wave index, 0..31
    const int q0 = jj * 32;
    const int ktmax = (q0 + 31) >> 6;
    const int pbase = (w * 32) * 72;           // this wave's Ps region

    // Q B-operand frags for both strips (loaded once, direct from global)
    short8 qa[2][2];
#pragma unroll
    for (int s = 0; s < 2; ++s)
#pragma unroll
        for (int h = 0; h < 2; ++h)
            qa[s][h] = *(const short8*)&qb[((bh * Np + q0 + s * 16 + ln) << 6) + h * 32 + quad * 8];

    f4 ot[2][4];   // O^T acc: [strip][nt]; row d = nt*16+quad*4+rg, col q = ln
#pragma unroll
    for (int s = 0; s < 2; ++s)
#pragma unroll
        for (int nt = 0; nt < 4; ++nt) ot[s][nt] = (f4){0.f, 0.f, 0.f, 0.f};
    float mrun[2] = {-INFINITY, -INFINITY}, lrun[2] = {0.f, 0.f};

    for (int kt = 0; kt <= ktmax; ++kt) {
        const bool diag = (kt == ktmax);   // masking only ever needed here

        // ---- S^T = K Q^T : K A-frags direct from global, shared by strips
        f4 st[2][4];
#pragma unroll
        for (int mt = 0; mt < 4; ++mt) {
            const int kmin = kt * 64 + mt * 16;
            if (diag && kmin > q0 + 31) {   // beyond both strips
                st[0][mt] = (f4){-INFINITY, -INFINITY, -INFINITY, -INFINITY};
                st[1][mt] = st[0][mt];
                continue;
            }
            const ushort* krow = &kb[((bh * Np + kmin + ln) << 6) + quad * 8];
            const short8 ka0 = *(const short8*)krow;
            const short8 ka1 = *(const short8*)(krow + 32);
#pragma unroll
            for (int s = 0; s < 2; ++s) {
                if (diag && kmin > q0 + s * 16 + 15) {
                    st[s][mt] = (f4){-INFINITY, -INFINITY, -INFINITY, -INFINITY};
                } else {
                    f4 z = (f4){0.f, 0.f, 0.f, 0.f};
                    z = __builtin_amdgcn_mfma_f32_16x16x32_bf16(ka0, qa[s][0], z, 0, 0, 0);
                    st[s][mt] = __builtin_amdgcn_mfma_f32_16x16x32_bf16(ka1, qa[s][1], z, 0, 0, 0);
                }
            }
        }

        if (diag) {   // elementwise causal mask: k > q -> -inf
#pragma unroll
            for (int s = 0; s < 2; ++s) {
                const int q = q0 + s * 16 + ln;
#pragma unroll
                for (int mt = 0; mt < 4; ++mt) {
                    const int kb_ = kt * 64 + mt * 16 + quad * 4;
#pragma unroll
                    for (int rg = 0; rg < 4; ++rg)
                        if (kb_ + rg > q) st[s][mt][rg] = -INFINITY;
                }
            }
        }

        // ---- online softmax per strip (state per lane: its q = ln)
#pragma unroll
        for (int s = 0; s < 2; ++s) {
            float mx = -INFINITY;
#pragma unroll
            for (int mt = 0; mt < 4; ++mt)
#pragma unroll
                for (int rg = 0; rg < 4; ++rg) mx = fmaxf(mx, st[s][mt][rg]);
            mx = fmaxf(mx, __shfl_xor(mx, 16));
            mx = fmaxf(mx, __shfl_xor(mx, 32));

            const float mn = fmaxf(mrun[s], mx);
            const float al = EXP2(mrun[s] - mn);
            mrun[s] = mn;

            float rs = 0.f;
            const int prow = pbase + (s * 16 + ln) * 72;
#pragma unroll
            for (int mt = 0; mt < 4; ++mt) {
                const float p0 = EXP2(st[s][mt][0] - mn), p1 = EXP2(st[s][mt][1] - mn);
                const float p2 = EXP2(st[s][mt][2] - mn), p3 = EXP2(st[s][mt][3] - mn);
                rs += (p0 + p1) + (p2 + p3);
                ushort4 u; u.x = f2b(p0); u.y = f2b(p1); u.z = f2b(p2); u.w = f2b(p3);
                *(ushort4*)&Ps[prow + mt * 16 + quad * 4] = u;
            }
            rs += __shfl_xor(rs, 16);
            rs += __shfl_xor(rs, 32);
            lrun[s] = lrun[s] * al + rs;

            // alpha-rescale O^T: cols are q = ln -> pure per-lane multiply
#pragma unroll
            for (int nt = 0; nt < 4; ++nt)
#pragma unroll
                for (int rg = 0; rg < 4; ++rg) ot[s][nt][rg] *= al;
        }

        // ---- O^T += V^T P^T : V A-frags direct from global, shared by strips
#pragma unroll
        for (int ks = 0; ks < 2; ++ks) {
            const int kminh = kt * 64 + ks * 32;
            if (diag && kminh > q0 + 31) continue;           // both strips done
            const bool use0 = !diag || (kminh <= q0 + 15);   // strip0 live?
            const short8 pa1 = *(const short8*)&Ps[pbase + (16 + ln) * 72 + ks * 32 + quad * 8];
            short8 pa0;
            if (use0) pa0 = *(const short8*)&Ps[pbase + (ln) * 72 + ks * 32 + quad * 8];
#pragma unroll
            for (int nt = 0; nt < 4; ++nt) {
                const short8 vf = *(const short8*)&vt[((size_t)bh << 16) +
                    ((nt * 16 + ln) << 10) + kminh + quad * 8];
                if (use0)
                    ot[0][nt] = __builtin_amdgcn_mfma_f32_16x16x32_bf16(vf, pa0, ot[0][nt], 0, 0, 0);
                ot[1][nt] = __builtin_amdgcn_mfma_f32_16x16x32_bf16(vf, pa1, ot[1][nt], 0, 0, 0);
            }
        }
    }

    // ---- epilogue: normalize, transpose via own Ps strip, coalesced store
#pragma unroll
    for (int s = 0; s < 2; ++s) {
        const float linv = 1.0f / lrun[s];
        const int prow = pbase + (s * 16 + ln) * 72;
#pragma unroll
        for (int nt = 0; nt < 4; ++nt) {
            ushort4 u;
            u.x = f2b(ot[s][nt][0] * linv);
            u.y = f2b(ot[s][nt][1] * linv);
            u.z = f2b(ot[s][nt][2] * linv);
            u.w = f2b(ot[s][nt][3] * linv);
            *(ushort4*)&Ps[prow + nt * 16 + quad * 4] = u;   // T[q=ln][d]
        }
        // read rows back (wave-private, in-order) and store coalesced
        const ushort* srow = &Ps[pbase + (s * 16 + ln) * 72 + quad * 16];
        ushort* drow = &ob[((bh * Np + q0 + s * 16 + ln) << 6) + quad * 16];
        *(uint4*)drow       = *(const uint4*)srow;
        *(uint4*)(drow + 8) = *(const uint4*)(srow + 8);
    }
}

// ---------------------------------------------------------------------------
// Kernel 3: projection GEMM, bf16 MFMA, 64(o) x 128(n) tile, BK=64.
// ---------------------------------------------------------------------------
__global__ __launch_bounds__(256)
void proj_gemm(const ushort* __restrict__ obuf, const ushort* __restrict__ pwb,
               const float* __restrict__ bias, float* __restrict__ out)
{
    __shared__ ushort As[64 * 72];    // pw [o][k]
    __shared__ ushort Bs[128 * 72];   // attn-out [n][k]

    const int t = threadIdx.x;
    const int w = t >> 6, lane = t & 63, quad = lane >> 4, ln = lane & 15;
    const int n0 = blockIdx.x * 128;
    const int o0 = blockIdx.y * 64;
    const int b  = blockIdx.z;
    const int nw = w * 32;

    f4 acc[4][2];
#pragma unroll
    for (int i = 0; i < 4; ++i)
#pragma unroll
        for (int j = 0; j < 2; ++j) acc[i][j] = (f4){0.f, 0.f, 0.f, 0.f};

    const int rr = t >> 2, cc = (t & 3) * 16;
    for (int k0 = 0; k0 < 512; k0 += 64) {
        __syncthreads();
        {   // A: 64 o-rows x 64 k; B: 128 n-rows x 64 k (one head per step)
            const ushort* sa = &pwb[(o0 + rr) * 512 + k0 + cc];
            *(uint4*)&As[rr * 72 + cc]     = *(const uint4*)sa;
            *(uint4*)&As[rr * 72 + cc + 8] = *(const uint4*)(sa + 8);
            const int head = k0 >> 6;
#pragma unroll
            for (int p = 0; p < 2; ++p) {
                const int row = rr + p * 64;
                const ushort* sb = &obuf[(((b * 8 + head) * Np + n0 + row) << 6) + cc];
                *(uint4*)&Bs[row * 72 + cc]     = *(const uint4*)sb;
                *(uint4*)&Bs[row * 72 + cc + 8] = *(const uint4*)(sb + 8);
            }
        }
        __syncthreads();
#pragma unroll
        for (int sub = 0; sub < 2; ++sub) {
            short8 af[4], bf[2];
#pragma unroll
            for (int ot = 0; ot < 4; ++ot)
                af[ot] = *(const short8*)&As[(ot * 16 + ln) * 72 + sub * 32 + quad * 8];
#pragma unroll
            for (int nt = 0; nt < 2; ++nt)
                bf[nt] = *(const short8*)&Bs[(nw + nt * 16 + ln) * 72 + sub * 32 + quad * 8];
#pragma unroll
            for (int ot = 0; ot < 4; ++ot)
#pragma unroll
                for (int nt = 0; nt < 2; ++nt)
                    acc[ot][nt] = __builtin_amdgcn_mfma_f32_16x16x32_bf16(
                        af[ot], bf[nt], acc[ot][nt], 0, 0, 0);
        }
    }

    // epilogue: direct fp32 stores, bias added
#pragma unroll
    for (int ot = 0; ot < 4; ++ot) {
#pragma unroll
        for (int rg = 0; rg < 4; ++rg) {
            const int oo = o0 + ot * 16 + quad * 4 + rg;
            const float pb = bias[oo];
            float* drow = &out[((b << 8) + oo) << 10];
#pragma unroll
            for (int nt = 0; nt < 2; ++nt)
                drow[n0 + nw + nt * 16 + ln] = acc[ot][nt][rg] + pb;
        }
    }
}

// ---------------------------------------------------------------------------
extern "C" void kernel_launch(void* const* d_in, const int* in_sizes, int n_in,
                              void* d_out, int out_size, void* d_ws, size_t ws_size,
                              hipStream_t stream)
{
    const float* x   = (const float*)d_in[0];   // [16,256,1024]
    const float* qw  = (const float*)d_in[1];   // [1536,256]
    const float* qbb = (const float*)d_in[2];   // [1536]
    const float* pw  = (const float*)d_in[3];   // [256,512]
    const float* pb  = (const float*)d_in[4];   // [256]
    float* out = (float*)d_out;                 // [16,256,1024]

    // workspace (all bf16): q/k [bh][n][64], v TRANSPOSED [bh][64][n],
    // attn-out [bh][n][64]; xb [b][n][c]; weights.
    const size_t per = (size_t)Bsz * 8 * Np * 64;
    ushort* qbuf = (ushort*)d_ws;
    ushort* kbuf = qbuf + per;
    ushort* vbuf = kbuf + per;
    ushort* obuf = vbuf + per;
    ushort* xb   = obuf + per;
    ushort* qwb  = xb + (size_t)Bsz * Np * Cin;
    ushort* pwb  = qwb + 1536 * Cin;

    cast_xw<<<dim3(16, 5, Bsz), 256, 0, stream>>>(x, qw, pw, xb, qwb, pwb);
    qkv_gemm<<<dim3(8, 12, Bsz), 256, 0, stream>>>(xb, qwb, qbb, qbuf, kbuf, vbuf);
    attn<<<dim3(128 * 8), 256, 0, stream>>>(qbuf, kbuf, vbuf, obuf);
    proj_gemm<<<dim3(8, 4, Bsz), 256, 0, stream>>>(obuf, pwb, pb, out);
}

// Round 8
// 173.165 us; speedup vs baseline: 1.1467x; 1.1467x over previous
//
#include <hip/hip_runtime.h>
#include <math.h>

// Problem constants: B=16, C_in=256, H=W=32 -> N=1024, qkv_out=1536,
// HEAD=8, dh=dv=64, V_DIM=512, OUT_CH=256.
static constexpr int Bsz = 16;
static constexpr int Np  = 1024;
static constexpr int Cin = 256;

typedef __attribute__((ext_vector_type(8))) short short8;  // 8 bf16 = 4 VGPR
typedef __attribute__((ext_vector_type(4))) float f4;      // mfma acc

// v_exp_f32 computes 2^x natively.
#if defined(__has_builtin)
#if __has_builtin(__builtin_amdgcn_exp2f)
#define EXP2(x) __builtin_amdgcn_exp2f(x)
#else
#define EXP2(x) exp2f(x)
#endif
#else
#define EXP2(x) exp2f(x)
#endif

// q pre-scale: dh^-0.5 * log2(e) (scores exit QK^T in log2 domain)
#define QSCALE 0.18033688011112f

// fp32 -> bf16 round-to-nearest-even
__device__ __forceinline__ unsigned short f2b(float f) {
    union { float fp; unsigned int u; } v; v.fp = f;
    unsigned int r = v.u + 0x7fffu + ((v.u >> 16) & 1u);
    return (unsigned short)(r >> 16);
}

// ---------------------------------------------------------------------------
// Kernel 0: cast+transpose x [b][c][n] fp32 -> xb [b][n][c] bf16 (y<4),
// and cast qkv_w / proj_w fp32 -> bf16 (y==4). Single launch.
// ---------------------------------------------------------------------------
__global__ __launch_bounds__(256)
void cast_xw(const float* __restrict__ x, const float* __restrict__ qw,
             const float* __restrict__ pw, ushort* __restrict__ xb,
             ushort* __restrict__ qwb, ushort* __restrict__ pwb)
{
    const int t = threadIdx.x;
    if (blockIdx.y < 4) {
        __shared__ ushort T[64][72];   // [n][c]
        const int n0 = blockIdx.x * 64, c0 = blockIdx.y * 64, b = blockIdx.z;
        {   // read 64c x 64n, convert, transposed scatter into LDS
            const int c_l = t >> 2, ns = (t & 3) * 16;
            const float* src = &x[((b * Cin + c0 + c_l) << 10) + n0 + ns];
#pragma unroll
            for (int i = 0; i < 4; ++i) {
                const float4 v = *(const float4*)(src + 4 * i);
                T[ns + 4 * i + 0][c_l] = f2b(v.x);
                T[ns + 4 * i + 1][c_l] = f2b(v.y);
                T[ns + 4 * i + 2][c_l] = f2b(v.z);
                T[ns + 4 * i + 3][c_l] = f2b(v.w);
            }
        }
        __syncthreads();
        {   // write rows of c (contiguous) to xb
            const int n_l = t >> 2, cs = (t & 3) * 16;
            ushort* dst = &xb[((b << 10) + n0 + n_l) * Cin + c0 + cs];
            *(uint4*)dst       = *(const uint4*)&T[n_l][cs];
            *(uint4*)(dst + 8) = *(const uint4*)&T[n_l][cs + 8];
        }
    } else {
        // weights: 524288 floats = 131072 float4; 256 blocks x 256 thr x 2
        const int nq4 = (1536 * Cin) / 4;
        const int base = ((blockIdx.z * 16 + blockIdx.x) * 256 + t) * 2;
#pragma unroll
        for (int g = 0; g < 2; ++g) {
            const int j = base + g;
            const float* src; ushort* dst; int jj;
            if (j < nq4) { src = qw; dst = qwb; jj = j; }
            else         { src = pw; dst = pwb; jj = j - nq4; }
            const float4 v = *(const float4*)(src + 4 * jj);
            ushort4 u; u.x = f2b(v.x); u.y = f2b(v.y); u.z = f2b(v.z); u.w = f2b(v.w);
            *(ushort4*)(dst + 4 * jj) = u;
        }
    }
}

// ---------------------------------------------------------------------------
// Kernel 1: QKV GEMM, bf16 MFMA 16x16x32, BK=64.
// Q/K o-tiles: C = W*X -> Ct [n][o] -> q/k [bh][n][64] (q pre-scaled QSCALE).
// V  o-tiles: swapped operands (C^T = X*W) -> vbuf TRANSPOSED [bh][d][n].
// ---------------------------------------------------------------------------
__global__ __launch_bounds__(256)
void qkv_gemm(const ushort* __restrict__ xb, const ushort* __restrict__ wb,
              const float* __restrict__ bias,
              ushort* __restrict__ qb, ushort* __restrict__ kb, ushort* __restrict__ vb)
{
    __shared__ ushort lds[18432];        // 36.9 KB; staging + epilogue alias
    ushort* As = lds;                    // [128 o][72]
    ushort* Bs = lds + 9216;             // [128 n][72]

    const int t = threadIdx.x;
    const int w = t >> 6, lane = t & 63, quad = lane >> 4, ln = lane & 15;
    const int n0 = blockIdx.x * 128;
    const int o0 = blockIdx.y * 128;
    const int b  = blockIdx.z;
    const int ow = (w & 1) * 64, nw = (w >> 1) * 64;
    const bool vpath = (o0 >= 1024);

    f4 acc[4][4];
#pragma unroll
    for (int i = 0; i < 4; ++i)
#pragma unroll
        for (int j = 0; j < 4; ++j) acc[i][j] = (f4){0.f, 0.f, 0.f, 0.f};

    const int rr = t >> 2, cc = (t & 3) * 16;
    for (int k0 = 0; k0 < Cin; k0 += 64) {
        __syncthreads();
#pragma unroll
        for (int p = 0; p < 2; ++p) {   // stage 128 rows x 64 k for A and B
            const int row = rr + p * 64;
            const ushort* sa = &wb[(o0 + row) * Cin + k0 + cc];
            *(uint4*)&As[row * 72 + cc]     = *(const uint4*)sa;
            *(uint4*)&As[row * 72 + cc + 8] = *(const uint4*)(sa + 8);
            const ushort* sb = &xb[((b << 10) + n0 + row) * Cin + k0 + cc];
            *(uint4*)&Bs[row * 72 + cc]     = *(const uint4*)sb;
            *(uint4*)&Bs[row * 72 + cc + 8] = *(const uint4*)(sb + 8);
        }
        __syncthreads();
#pragma unroll
        for (int sub = 0; sub < 2; ++sub) {
            short8 af[4], bf[4];
#pragma unroll
            for (int ot = 0; ot < 4; ++ot)
                af[ot] = *(const short8*)&As[(ow + ot * 16 + ln) * 72 + sub * 32 + quad * 8];
#pragma unroll
            for (int nt = 0; nt < 4; ++nt)
                bf[nt] = *(const short8*)&Bs[(nw + nt * 16 + ln) * 72 + sub * 32 + quad * 8];
            if (!vpath) {   // acc[ot][nt]: row = o, col = n
#pragma unroll
                for (int ot = 0; ot < 4; ++ot)
#pragma unroll
                    for (int nt = 0; nt < 4; ++nt)
                        acc[ot][nt] = __builtin_amdgcn_mfma_f32_16x16x32_bf16(
                            af[ot], bf[nt], acc[ot][nt], 0, 0, 0);
            } else {        // acc[nt][ot]: row = n, col = o (transposed C)
#pragma unroll
                for (int nt = 0; nt < 4; ++nt)
#pragma unroll
                    for (int ot = 0; ot < 4; ++ot)
                        acc[nt][ot] = __builtin_amdgcn_mfma_f32_16x16x32_bf16(
                            bf[nt], af[ot], acc[nt][ot], 0, 0, 0);
            }
        }
    }

    __syncthreads();                     // staging reads done; alias lds
    if (!vpath) {
        // ---- Q/K epilogue: Ct [n][136 o-stride] ----
        ushort* Ct = lds;
        const float sc = (o0 < 512) ? QSCALE : 1.0f;
#pragma unroll
        for (int ot = 0; ot < 4; ++ot) {
            float bs[4];
#pragma unroll
            for (int rg = 0; rg < 4; ++rg)
                bs[rg] = bias[o0 + ow + ot * 16 + quad * 4 + rg];
#pragma unroll
            for (int nt = 0; nt < 4; ++nt) {
                ushort4 u;
                u.x = f2b((acc[ot][nt][0] + bs[0]) * sc);
                u.y = f2b((acc[ot][nt][1] + bs[1]) * sc);
                u.z = f2b((acc[ot][nt][2] + bs[2]) * sc);
                u.w = f2b((acc[ot][nt][3] + bs[3]) * sc);
                *(ushort4*)&Ct[(nw + nt * 16 + ln) * 136 + ow + ot * 16 + quad * 4] = u;
            }
        }
        __syncthreads();
        ushort* dst; int obase;
        if (o0 < 512) { dst = qb; obase = o0; }
        else          { dst = kb; obase = o0 - 512; }
        const int rn = t >> 1, hf = t & 1;
        const int bh = b * 8 + (obase >> 6) + hf;
        ushort* drow = &dst[(bh * Np + n0 + rn) << 6];
        const ushort* srow = &Ct[rn * 136 + hf * 64];
#pragma unroll
        for (int s = 0; s < 8; ++s)
            *(uint4*)(drow + s * 8) = *(const uint4*)(srow + s * 8);
    } else {
        // ---- V epilogue: Ct [o][136 n-stride] (rows = d), then [bh][d][n] ----
        ushort* Ct = lds;
#pragma unroll
        for (int ot = 0; ot < 4; ++ot) {
            const float bo = bias[o0 + ow + ot * 16 + ln];
#pragma unroll
            for (int nt = 0; nt < 4; ++nt) {
                ushort4 u;
                u.x = f2b(acc[nt][ot][0] + bo);
                u.y = f2b(acc[nt][ot][1] + bo);
                u.z = f2b(acc[nt][ot][2] + bo);
                u.w = f2b(acc[nt][ot][3] + bo);
                *(ushort4*)&Ct[(ow + ot * 16 + ln) * 136 + nw + nt * 16 + quad * 4] = u;
            }
        }
        __syncthreads();
        const int o_l = t >> 1, nh = (t & 1) * 64;
        const int bh = b * 8 + ((o0 - 1024) >> 6) + (o_l >> 6);
        ushort* drow = &vb[((size_t)bh << 16) + ((o_l & 63) << 10) + n0 + nh];
        const ushort* srow = &Ct[o_l * 136 + nh];
#pragma unroll
        for (int s = 0; s < 8; ++s)
            *(uint4*)(drow + s * 8) = *(const uint4*)(srow + s * 8);
    }
}

// ---------------------------------------------------------------------------
// Kernel 2: causal flash attention, bf16 MFMA, LDS-staged K/V (R6 structure)
// with 128 q-rows per block: each wave owns 32 q-rows (2 strips of 16), so
// each staging/barrier pair feeds 32 MFMAs/wave (2x R6). Q frags direct from
// global (once). O^T = V^T*P^T accumulation (same LDS reads, operand swap):
// alpha-rescale is per-lane, epilogue transposes via wave-private Ps.
// Softmax in log2 domain. LDS 36.9 KB -> 4 blocks/CU.
// ---------------------------------------------------------------------------
__global__ __launch_bounds__(256)
void attn(const ushort* __restrict__ qb, const ushort* __restrict__ kb,
          const ushort* __restrict__ vt, ushort* __restrict__ ob)
{
    __shared__ ushort Ks[64 * 72];    // [k][d]
    __shared__ ushort Vt[64 * 72];    // [d][k]
    __shared__ ushort Ps[128 * 72];   // [q][k], 32 rows per wave

    const int t = threadIdx.x;
    const int w = t >> 6, lane = t & 63, quad = lane >> 4, ln = lane & 15;
    const int bh  = blockIdx.x & 127;
    const int qp  = 7 - (blockIdx.x >> 7);   // heavy q-blocks first
    const int qb0 = qp * 128;
    const int q0  = qb0 + w * 32;            // this wave's 32 q-rows
    const int ktmax_w   = q0 >> 6;
    const int ktmax_blk = 2 * qp + 1;
    const int pbase = (w * 32) * 72;

    // Q B-operand frags for both strips (loaded once, direct from global)
    short8 qa[2][2];
#pragma unroll
    for (int s = 0; s < 2; ++s)
#pragma unroll
        for (int h = 0; h < 2; ++h)
            qa[s][h] = *(const short8*)&qb[((bh * Np + q0 + s * 16 + ln) << 6) + h * 32 + quad * 8];

    f4 ot[2][4];   // O^T acc: [strip][nt]; row d = nt*16+quad*4+rg, col q = ln
#pragma unroll
    for (int s = 0; s < 2; ++s)
#pragma unroll
        for (int nt = 0; nt < 4; ++nt) ot[s][nt] = (f4){0.f, 0.f, 0.f, 0.f};
    float mrun[2] = {-INFINITY, -INFINITY}, lrun[2] = {0.f, 0.f};

    const int rr = t >> 2, cc = (t & 3) * 16;
    for (int kt = 0; kt <= ktmax_blk; ++kt) {
        __syncthreads();   // prior-iter Ks/Vt reads done before overwrite
        {   // stage K [k][d] and Vt [d][k] (both pure vector copies)
            const ushort* sk = &kb[((bh * Np + kt * 64 + rr) << 6) + cc];
            *(uint4*)&Ks[rr * 72 + cc]     = *(const uint4*)sk;
            *(uint4*)&Ks[rr * 72 + cc + 8] = *(const uint4*)(sk + 8);
            const ushort* sv = &vt[((size_t)bh << 16) + (rr << 10) + kt * 64 + cc];
            *(uint4*)&Vt[rr * 72 + cc]     = *(const uint4*)sv;
            *(uint4*)&Vt[rr * 72 + cc + 8] = *(const uint4*)(sv + 8);
        }
        __syncthreads();
        if (kt > ktmax_w) continue;       // beyond this wave's causal range
        const bool diag = (kt == ktmax_w);

        // ---- S^T = K Q^T : rows k, cols q = ln (log2 domain)
        f4 st[2][4];
#pragma unroll
        for (int mt = 0; mt < 4; ++mt) {
            const int kmin = kt * 64 + mt * 16;
            if (diag && kmin > q0 + 31) {   // beyond both strips
                st[0][mt] = (f4){-INFINITY, -INFINITY, -INFINITY, -INFINITY};
                st[1][mt] = st[0][mt];
                continue;
            }
            const short8 ka0 = *(const short8*)&Ks[(mt * 16 + ln) * 72 + quad * 8];
            const short8 ka1 = *(const short8*)&Ks[(mt * 16 + ln) * 72 + 32 + quad * 8];
#pragma unroll
            for (int s = 0; s < 2; ++s) {
                if (diag && kmin > q0 + s * 16 + 15) {
                    st[s][mt] = (f4){-INFINITY, -INFINITY, -INFINITY, -INFINITY};
                } else {
                    f4 z = (f4){0.f, 0.f, 0.f, 0.f};
                    z = __builtin_amdgcn_mfma_f32_16x16x32_bf16(ka0, qa[s][0], z, 0, 0, 0);
                    st[s][mt] = __builtin_amdgcn_mfma_f32_16x16x32_bf16(ka1, qa[s][1], z, 0, 0, 0);
                }
            }
        }

        if (diag) {   // elementwise causal mask: k > q -> -inf
#pragma unroll
            for (int s = 0; s < 2; ++s) {
                const int q = q0 + s * 16 + ln;
#pragma unroll
                for (int mt = 0; mt < 4; ++mt) {
                    const int kb_ = kt * 64 + mt * 16 + quad * 4;
#pragma unroll
                    for (int rg = 0; rg < 4; ++rg)
                        if (kb_ + rg > q) st[s][mt][rg] = -INFINITY;
                }
            }
        }

        // ---- online softmax per strip (state per lane: its q = ln)
#pragma unroll
        for (int s = 0; s < 2; ++s) {
            float mx = -INFINITY;
#pragma unroll
            for (int mt = 0; mt < 4; ++mt)
#pragma unroll
                for (int rg = 0; rg < 4; ++rg) mx = fmaxf(mx, st[s][mt][rg]);
            mx = fmaxf(mx, __shfl_xor(mx, 16));
            mx = fmaxf(mx, __shfl_xor(mx, 32));

            const float mn = fmaxf(mrun[s], mx);
            const float al = EXP2(mrun[s] - mn);
            mrun[s] = mn;

            float rs = 0.f;
            const int prow = pbase + (s * 16 + ln) * 72;
#pragma unroll
            for (int mt = 0; mt < 4; ++mt) {
                const float p0 = EXP2(st[s][mt][0] - mn), p1 = EXP2(st[s][mt][1] - mn);
                const float p2 = EXP2(st[s][mt][2] - mn), p3 = EXP2(st[s][mt][3] - mn);
                rs += (p0 + p1) + (p2 + p3);
                ushort4 u; u.x = f2b(p0); u.y = f2b(p1); u.z = f2b(p2); u.w = f2b(p3);
                *(ushort4*)&Ps[prow + mt * 16 + quad * 4] = u;
            }
            rs += __shfl_xor(rs, 16);
            rs += __shfl_xor(rs, 32);
            lrun[s] = lrun[s] * al + rs;

            // alpha-rescale O^T: cols are q = ln -> pure per-lane multiply
#pragma unroll
            for (int nt = 0; nt < 4; ++nt)
#pragma unroll
                for (int rg = 0; rg < 4; ++rg) ot[s][nt][rg] *= al;
        }

        // ---- O^T += V^T P^T (A-frags from Vt LDS, shared by strips)
#pragma unroll
        for (int ks = 0; ks < 2; ++ks) {
            const int kminh = kt * 64 + ks * 32;
            if (diag && kminh > q0 + 31) continue;           // both strips done
            const bool use0 = !diag || (kminh <= q0 + 15);   // strip0 live?
            const short8 pa1 = *(const short8*)&Ps[pbase + (16 + ln) * 72 + ks * 32 + quad * 8];
            short8 pa0;
            if (use0) pa0 = *(const short8*)&Ps[pbase + ln * 72 + ks * 32 + quad * 8];
#pragma unroll
            for (int nt = 0; nt < 4; ++nt) {
                const short8 vf = *(const short8*)&Vt[(nt * 16 + ln) * 72 + ks * 32 + quad * 8];
                if (use0)
                    ot[0][nt] = __builtin_amdgcn_mfma_f32_16x16x32_bf16(vf, pa0, ot[0][nt], 0, 0, 0);
                ot[1][nt] = __builtin_amdgcn_mfma_f32_16x16x32_bf16(vf, pa1, ot[1][nt], 0, 0, 0);
            }
        }
    }

    // ---- epilogue: normalize, transpose via own Ps strip, coalesced store
#pragma unroll
    for (int s = 0; s < 2; ++s) {
        const float linv = 1.0f / lrun[s];
        const int prow = pbase + (s * 16 + ln) * 72;
#pragma unroll
        for (int nt = 0; nt < 4; ++nt) {
            ushort4 u;
            u.x = f2b(ot[s][nt][0] * linv);
            u.y = f2b(ot[s][nt][1] * linv);
            u.z = f2b(ot[s][nt][2] * linv);
            u.w = f2b(ot[s][nt][3] * linv);
            *(ushort4*)&Ps[prow + nt * 16 + quad * 4] = u;   // T[q=ln][d]
        }
        const ushort* srow = &Ps[prow + quad * 16];
        ushort* drow = &ob[((bh * Np + q0 + s * 16 + ln) << 6) + quad * 16];
        *(uint4*)drow       = *(const uint4*)srow;
        *(uint4*)(drow + 8) = *(const uint4*)(srow + 8);
    }
}

// ---------------------------------------------------------------------------
// Kernel 3: projection GEMM, bf16 MFMA, 64(o) x 128(n) tile, BK=64.
// ---------------------------------------------------------------------------
__global__ __launch_bounds__(256)
void proj_gemm(const ushort* __restrict__ obuf, const ushort* __restrict__ pwb,
               const float* __restrict__ bias, float* __restrict__ out)
{
    __shared__ ushort As[64 * 72];    // pw [o][k]
    __shared__ ushort Bs[128 * 72];   // attn-out [n][k]

    const int t = threadIdx.x;
    const int w = t >> 6, lane = t & 63, quad = lane >> 4, ln = lane & 15;
    const int n0 = blockIdx.x * 128;
    const int o0 = blockIdx.y * 64;
    const int b  = blockIdx.z;
    const int nw = w * 32;

    f4 acc[4][2];
#pragma unroll
    for (int i = 0; i < 4; ++i)
#pragma unroll
        for (int j = 0; j < 2; ++j) acc[i][j] = (f4){0.f, 0.f, 0.f, 0.f};

    const int rr = t >> 2, cc = (t & 3) * 16;
    for (int k0 = 0; k0 < 512; k0 += 64) {
        __syncthreads();
        {   // A: 64 o-rows x 64 k; B: 128 n-rows x 64 k (one head per step)
            const ushort* sa = &pwb[(o0 + rr) * 512 + k0 + cc];
            *(uint4*)&As[rr * 72 + cc]     = *(const uint4*)sa;
            *(uint4*)&As[rr * 72 + cc + 8] = *(const uint4*)(sa + 8);
            const int head = k0 >> 6;
#pragma unroll
            for (int p = 0; p < 2; ++p) {
                const int row = rr + p * 64;
                const ushort* sb = &obuf[(((b * 8 + head) * Np + n0 + row) << 6) + cc];
                *(uint4*)&Bs[row * 72 + cc]     = *(const uint4*)sb;
                *(uint4*)&Bs[row * 72 + cc + 8] = *(const uint4*)(sb + 8);
            }
        }
        __syncthreads();
#pragma unroll
        for (int sub = 0; sub < 2; ++sub) {
            short8 af[4], bf[2];
#pragma unroll
            for (int ot = 0; ot < 4; ++ot)
                af[ot] = *(const short8*)&As[(ot * 16 + ln) * 72 + sub * 32 + quad * 8];
#pragma unroll
            for (int nt = 0; nt < 2; ++nt)
                bf[nt] = *(const short8*)&Bs[(nw + nt * 16 + ln) * 72 + sub * 32 + quad * 8];
#pragma unroll
            for (int ot = 0; ot < 4; ++ot)
#pragma unroll
                for (int nt = 0; nt < 2; ++nt)
                    acc[ot][nt] = __builtin_amdgcn_mfma_f32_16x16x32_bf16(
                        af[ot], bf[nt], acc[ot][nt], 0, 0, 0);
        }
    }

    // epilogue: direct fp32 stores, bias added
#pragma unroll
    for (int ot = 0; ot < 4; ++ot) {
#pragma unroll
        for (int rg = 0; rg < 4; ++rg) {
            const int oo = o0 + ot * 16 + quad * 4 + rg;
            const float pb = bias[oo];
            float* drow = &out[((b << 8) + oo) << 10];
#pragma unroll
            for (int nt = 0; nt < 2; ++nt)
                drow[n0 + nw + nt * 16 + ln] = acc[ot][nt][rg] + pb;
        }
    }
}

// ---------------------------------------------------------------------------
extern "C" void kernel_launch(void* const* d_in, const int* in_sizes, int n_in,
                              void* d_out, int out_size, void* d_ws, size_t ws_size,
                              hipStream_t stream)
{
    const float* x   = (const float*)d_in[0];   // [16,256,1024]
    const float* qw  = (const float*)d_in[1];   // [1536,256]
    const float* qbb = (const float*)d_in[2];   // [1536]
    const float* pw  = (const float*)d_in[3];   // [256,512]
    const float* pb  = (const float*)d_in[4];   // [256]
    float* out = (float*)d_out;                 // [16,256,1024]

    // workspace (all bf16): q/k [bh][n][64], v TRANSPOSED [bh][64][n],
    // attn-out [bh][n][64]; xb [b][n][c]; weights.
    const size_t per = (size_t)Bsz * 8 * Np * 64;
    ushort* qbuf = (ushort*)d_ws;
    ushort* kbuf = qbuf + per;
    ushort* vbuf = kbuf + per;
    ushort* obuf = vbuf + per;
    ushort* xb   = obuf + per;
    ushort* qwb  = xb + (size_t)Bsz * Np * Cin;
    ushort* pwb  = qwb + 1536 * Cin;

    cast_xw<<<dim3(16, 5, Bsz), 256, 0, stream>>>(x, qw, pw, xb, qwb, pwb);
    qkv_gemm<<<dim3(8, 12, Bsz), 256, 0, stream>>>(xb, qwb, qbb, qbuf, kbuf, vbuf);
    attn<<<dim3(128 * 8), 256, 0, stream>>>(qbuf, kbuf, vbuf, obuf);
    proj_gemm<<<dim3(8, 4, Bsz), 256, 0, stream>>>(obuf, pwb, pb, out);
}

// Round 9
// 168.257 us; speedup vs baseline: 1.1801x; 1.0292x over previous
//
#include <hip/hip_runtime.h>
#include <math.h>

// Problem constants: B=16, C_in=256, H=W=32 -> N=1024, qkv_out=1536,
// HEAD=8, dh=dv=64, V_DIM=512, OUT_CH=256.
static constexpr int Bsz = 16;
static constexpr int Np  = 1024;
static constexpr int Cin = 256;

typedef __attribute__((ext_vector_type(8))) short short8;  // 8 bf16 = 4 VGPR
typedef __attribute__((ext_vector_type(4))) float f4;      // mfma acc

// v_exp_f32 computes 2^x natively.
#if defined(__has_builtin)
#if __has_builtin(__builtin_amdgcn_exp2f)
#define EXP2(x) __builtin_amdgcn_exp2f(x)
#else
#define EXP2(x) exp2f(x)
#endif
#else
#define EXP2(x) exp2f(x)
#endif

// q pre-scale: dh^-0.5 * log2(e) (scores exit QK^T in log2 domain)
#define QSCALE 0.18033688011112f

// fp32 -> bf16 round-to-nearest-even
__device__ __forceinline__ unsigned short f2b(float f) {
    union { float fp; unsigned int u; } v; v.fp = f;
    unsigned int r = v.u + 0x7fffu + ((v.u >> 16) & 1u);
    return (unsigned short)(r >> 16);
}

// ---------------------------------------------------------------------------
// Kernel 0: cast+transpose x [b][c][n] fp32 -> xb [b][n][c] bf16 (y<4),
// and cast qkv_w / proj_w fp32 -> bf16 (y==4). Single launch.
// ---------------------------------------------------------------------------
__global__ __launch_bounds__(256)
void cast_xw(const float* __restrict__ x, const float* __restrict__ qw,
             const float* __restrict__ pw, ushort* __restrict__ xb,
             ushort* __restrict__ qwb, ushort* __restrict__ pwb)
{
    const int t = threadIdx.x;
    if (blockIdx.y < 4) {
        __shared__ ushort T[64][72];   // [n][c]
        const int n0 = blockIdx.x * 64, c0 = blockIdx.y * 64, b = blockIdx.z;
        {   // read 64c x 64n, convert, transposed scatter into LDS
            const int c_l = t >> 2, ns = (t & 3) * 16;
            const float* src = &x[((b * Cin + c0 + c_l) << 10) + n0 + ns];
#pragma unroll
            for (int i = 0; i < 4; ++i) {
                const float4 v = *(const float4*)(src + 4 * i);
                T[ns + 4 * i + 0][c_l] = f2b(v.x);
                T[ns + 4 * i + 1][c_l] = f2b(v.y);
                T[ns + 4 * i + 2][c_l] = f2b(v.z);
                T[ns + 4 * i + 3][c_l] = f2b(v.w);
            }
        }
        __syncthreads();
        {   // write rows of c (contiguous) to xb
            const int n_l = t >> 2, cs = (t & 3) * 16;
            ushort* dst = &xb[((b << 10) + n0 + n_l) * Cin + c0 + cs];
            *(uint4*)dst       = *(const uint4*)&T[n_l][cs];
            *(uint4*)(dst + 8) = *(const uint4*)&T[n_l][cs + 8];
        }
    } else {
        // weights: 524288 floats = 131072 float4; 256 blocks x 256 thr x 2
        const int nq4 = (1536 * Cin) / 4;
        const int base = ((blockIdx.z * 16 + blockIdx.x) * 256 + t) * 2;
#pragma unroll
        for (int g = 0; g < 2; ++g) {
            const int j = base + g;
            const float* src; ushort* dst; int jj;
            if (j < nq4) { src = qw; dst = qwb; jj = j; }
            else         { src = pw; dst = pwb; jj = j - nq4; }
            const float4 v = *(const float4*)(src + 4 * jj);
            ushort4 u; u.x = f2b(v.x); u.y = f2b(v.y); u.z = f2b(v.z); u.w = f2b(v.w);
            *(ushort4*)(dst + 4 * jj) = u;
        }
    }
}

// ---------------------------------------------------------------------------
// Kernel 1: QKV GEMM, bf16 MFMA 16x16x32, BK=64.
// Q/K o-tiles: C = W*X -> Ct [n][o] -> q/k [bh][n][64] (q pre-scaled QSCALE).
// V  o-tiles: swapped operands (C^T = X*W) -> vbuf TRANSPOSED [bh][d][n].
// ---------------------------------------------------------------------------
__global__ __launch_bounds__(256)
void qkv_gemm(const ushort* __restrict__ xb, const ushort* __restrict__ wb,
              const float* __restrict__ bias,
              ushort* __restrict__ qb, ushort* __restrict__ kb, ushort* __restrict__ vb)
{
    __shared__ ushort lds[18432];        // 36.9 KB; staging + epilogue alias
    ushort* As = lds;                    // [128 o][72]
    ushort* Bs = lds + 9216;             // [128 n][72]

    const int t = threadIdx.x;
    const int w = t >> 6, lane = t & 63, quad = lane >> 4, ln = lane & 15;
    const int n0 = blockIdx.x * 128;
    const int o0 = blockIdx.y * 128;
    const int b  = blockIdx.z;
    const int ow = (w & 1) * 64, nw = (w >> 1) * 64;
    const bool vpath = (o0 >= 1024);

    f4 acc[4][4];
#pragma unroll
    for (int i = 0; i < 4; ++i)
#pragma unroll
        for (int j = 0; j < 4; ++j) acc[i][j] = (f4){0.f, 0.f, 0.f, 0.f};

    const int rr = t >> 2, cc = (t & 3) * 16;
    for (int k0 = 0; k0 < Cin; k0 += 64) {
        __syncthreads();
#pragma unroll
        for (int p = 0; p < 2; ++p) {   // stage 128 rows x 64 k for A and B
            const int row = rr + p * 64;
            const ushort* sa = &wb[(o0 + row) * Cin + k0 + cc];
            *(uint4*)&As[row * 72 + cc]     = *(const uint4*)sa;
            *(uint4*)&As[row * 72 + cc + 8] = *(const uint4*)(sa + 8);
            const ushort* sb = &xb[((b << 10) + n0 + row) * Cin + k0 + cc];
            *(uint4*)&Bs[row * 72 + cc]     = *(const uint4*)sb;
            *(uint4*)&Bs[row * 72 + cc + 8] = *(const uint4*)(sb + 8);
        }
        __syncthreads();
#pragma unroll
        for (int sub = 0; sub < 2; ++sub) {
            short8 af[4], bf[4];
#pragma unroll
            for (int ot = 0; ot < 4; ++ot)
                af[ot] = *(const short8*)&As[(ow + ot * 16 + ln) * 72 + sub * 32 + quad * 8];
#pragma unroll
            for (int nt = 0; nt < 4; ++nt)
                bf[nt] = *(const short8*)&Bs[(nw + nt * 16 + ln) * 72 + sub * 32 + quad * 8];
            if (!vpath) {   // acc[ot][nt]: row = o, col = n
#pragma unroll
                for (int ot = 0; ot < 4; ++ot)
#pragma unroll
                    for (int nt = 0; nt < 4; ++nt)
                        acc[ot][nt] = __builtin_amdgcn_mfma_f32_16x16x32_bf16(
                            af[ot], bf[nt], acc[ot][nt], 0, 0, 0);
            } else {        // acc[nt][ot]: row = n, col = o (transposed C)
#pragma unroll
                for (int nt = 0; nt < 4; ++nt)
#pragma unroll
                    for (int ot = 0; ot < 4; ++ot)
                        acc[nt][ot] = __builtin_amdgcn_mfma_f32_16x16x32_bf16(
                            bf[nt], af[ot], acc[nt][ot], 0, 0, 0);
            }
        }
    }

    __syncthreads();                     // staging reads done; alias lds
    if (!vpath) {
        // ---- Q/K epilogue: Ct [n][136 o-stride] ----
        ushort* Ct = lds;
        const float sc = (o0 < 512) ? QSCALE : 1.0f;
#pragma unroll
        for (int ot = 0; ot < 4; ++ot) {
            float bs[4];
#pragma unroll
            for (int rg = 0; rg < 4; ++rg)
                bs[rg] = bias[o0 + ow + ot * 16 + quad * 4 + rg];
#pragma unroll
            for (int nt = 0; nt < 4; ++nt) {
                ushort4 u;
                u.x = f2b((acc[ot][nt][0] + bs[0]) * sc);
                u.y = f2b((acc[ot][nt][1] + bs[1]) * sc);
                u.z = f2b((acc[ot][nt][2] + bs[2]) * sc);
                u.w = f2b((acc[ot][nt][3] + bs[3]) * sc);
                *(ushort4*)&Ct[(nw + nt * 16 + ln) * 136 + ow + ot * 16 + quad * 4] = u;
            }
        }
        __syncthreads();
        ushort* dst; int obase;
        if (o0 < 512) { dst = qb; obase = o0; }
        else          { dst = kb; obase = o0 - 512; }
        const int rn = t >> 1, hf = t & 1;
        const int bh = b * 8 + (obase >> 6) + hf;
        ushort* drow = &dst[(bh * Np + n0 + rn) << 6];
        const ushort* srow = &Ct[rn * 136 + hf * 64];
#pragma unroll
        for (int s = 0; s < 8; ++s)
            *(uint4*)(drow + s * 8) = *(const uint4*)(srow + s * 8);
    } else {
        // ---- V epilogue: Ct [o][136 n-stride] (rows = d), then [bh][d][n] ----
        ushort* Ct = lds;
#pragma unroll
        for (int ot = 0; ot < 4; ++ot) {
            const float bo = bias[o0 + ow + ot * 16 + ln];
#pragma unroll
            for (int nt = 0; nt < 4; ++nt) {
                ushort4 u;
                u.x = f2b(acc[nt][ot][0] + bo);
                u.y = f2b(acc[nt][ot][1] + bo);
                u.z = f2b(acc[nt][ot][2] + bo);
                u.w = f2b(acc[nt][ot][3] + bo);
                *(ushort4*)&Ct[(ow + ot * 16 + ln) * 136 + nw + nt * 16 + quad * 4] = u;
            }
        }
        __syncthreads();
        const int o_l = t >> 1, nh = (t & 1) * 64;
        const int bh = b * 8 + ((o0 - 1024) >> 6) + (o_l >> 6);
        ushort* drow = &vb[((size_t)bh << 16) + ((o_l & 63) << 10) + n0 + nh];
        const ushort* srow = &Ct[o_l * 136 + nh];
#pragma unroll
        for (int s = 0; s < 8; ++s)
            *(uint4*)(drow + s * 8) = *(const uint4*)(srow + s * 8);
    }
}

// ---------------------------------------------------------------------------
// Kernel 2: causal flash attention, bf16 MFMA. 128-THREAD blocks (2 waves),
// block covers 64 q-rows, wave owns 32 (2 strips of 16) -> K-frag LDS reads
// shared by 2 MFMAs, ~1.4x fewer ds-instr per q-row than the 16-row/wave
// version, while keeping the 2048-block fine-grained schedule. Both waves
// share the same causal range (no idle-wave waste). Q frags direct from
// global (once). O^T = V^T*P^T: alpha-rescale per-lane; epilogue transposes
// via wave-private Ps. Softmax in log2 domain. LDS 27.6 KB -> 5 blocks/CU.
// ---------------------------------------------------------------------------
__global__ __launch_bounds__(128)
void attn(const ushort* __restrict__ qb, const ushort* __restrict__ kb,
          const ushort* __restrict__ vt, ushort* __restrict__ ob)
{
    __shared__ ushort Ks[64 * 72];    // [k][d]
    __shared__ ushort Vt[64 * 72];    // [d][k]
    __shared__ ushort Ps[64 * 72];    // [q][k], 32 rows per wave

    const int t = threadIdx.x;
    const int w = t >> 6, lane = t & 63, quad = lane >> 4, ln = lane & 15;
    const int bh = blockIdx.x & 127;
    const int qt = 15 - (blockIdx.x >> 7);   // heavy q-blocks first
    const int q0 = qt * 64 + w * 32;         // this wave's 32 q-rows
    const int pbase = (w * 32) * 72;

    // Q B-operand frags for both strips (loaded once, direct from global)
    short8 qa[2][2];
#pragma unroll
    for (int s = 0; s < 2; ++s)
#pragma unroll
        for (int h = 0; h < 2; ++h)
            qa[s][h] = *(const short8*)&qb[((bh * Np + q0 + s * 16 + ln) << 6) + h * 32 + quad * 8];

    f4 ot[2][4];   // O^T acc: [strip][nt]; row d = nt*16+quad*4+rg, col q = ln
#pragma unroll
    for (int s = 0; s < 2; ++s)
#pragma unroll
        for (int nt = 0; nt < 4; ++nt) ot[s][nt] = (f4){0.f, 0.f, 0.f, 0.f};
    float mrun[2] = {-INFINITY, -INFINITY}, lrun[2] = {0.f, 0.f};

    const int rr = t >> 1, cc = (t & 1) * 32;   // staging: 2 rows/thread-pair
    for (int kt = 0; kt <= qt; ++kt) {
        __syncthreads();   // prior-iter Ks/Vt reads done before overwrite
        {   // stage K [k][d] and Vt [d][k]: 4 uint4 per thread
            const ushort* sk = &kb[((bh * Np + kt * 64 + rr) << 6) + cc];
            *(uint4*)&Ks[rr * 72 + cc]     = *(const uint4*)sk;
            *(uint4*)&Ks[rr * 72 + cc + 8] = *(const uint4*)(sk + 8);
            *(uint4*)&Ks[rr * 72 + cc + 16] = *(const uint4*)(sk + 16);
            *(uint4*)&Ks[rr * 72 + cc + 24] = *(const uint4*)(sk + 24);
            const ushort* sv = &vt[((size_t)bh << 16) + (rr << 10) + kt * 64 + cc];
            *(uint4*)&Vt[rr * 72 + cc]     = *(const uint4*)sv;
            *(uint4*)&Vt[rr * 72 + cc + 8] = *(const uint4*)(sv + 8);
            *(uint4*)&Vt[rr * 72 + cc + 16] = *(const uint4*)(sv + 16);
            *(uint4*)&Vt[rr * 72 + cc + 24] = *(const uint4*)(sv + 24);
        }
        __syncthreads();
        const bool diag = (kt == qt);

        // ---- S^T = K Q^T : rows k, cols q = ln (log2 domain)
        f4 st[2][4];
#pragma unroll
        for (int mt = 0; mt < 4; ++mt) {
            const int kmin = kt * 64 + mt * 16;
            if (diag && kmin > q0 + 31) {   // beyond both strips
                st[0][mt] = (f4){-INFINITY, -INFINITY, -INFINITY, -INFINITY};
                st[1][mt] = st[0][mt];
                continue;
            }
            const short8 ka0 = *(const short8*)&Ks[(mt * 16 + ln) * 72 + quad * 8];
            const short8 ka1 = *(const short8*)&Ks[(mt * 16 + ln) * 72 + 32 + quad * 8];
#pragma unroll
            for (int s = 0; s < 2; ++s) {
                if (diag && kmin > q0 + s * 16 + 15) {
                    st[s][mt] = (f4){-INFINITY, -INFINITY, -INFINITY, -INFINITY};
                } else {
                    f4 z = (f4){0.f, 0.f, 0.f, 0.f};
                    z = __builtin_amdgcn_mfma_f32_16x16x32_bf16(ka0, qa[s][0], z, 0, 0, 0);
                    st[s][mt] = __builtin_amdgcn_mfma_f32_16x16x32_bf16(ka1, qa[s][1], z, 0, 0, 0);
                }
            }
        }

        if (diag) {   // elementwise causal mask: k > q -> -inf
#pragma unroll
            for (int s = 0; s < 2; ++s) {
                const int q = q0 + s * 16 + ln;
#pragma unroll
                for (int mt = 0; mt < 4; ++mt) {
                    const int kb_ = kt * 64 + mt * 16 + quad * 4;
#pragma unroll
                    for (int rg = 0; rg < 4; ++rg)
                        if (kb_ + rg > q) st[s][mt][rg] = -INFINITY;
                }
            }
        }

        // ---- online softmax per strip (state per lane: its q = ln)
#pragma unroll
        for (int s = 0; s < 2; ++s) {
            float mx = -INFINITY;
#pragma unroll
            for (int mt = 0; mt < 4; ++mt)
#pragma unroll
                for (int rg = 0; rg < 4; ++rg) mx = fmaxf(mx, st[s][mt][rg]);
            mx = fmaxf(mx, __shfl_xor(mx, 16));
            mx = fmaxf(mx, __shfl_xor(mx, 32));

            const float mn = fmaxf(mrun[s], mx);
            const float al = EXP2(mrun[s] - mn);
            mrun[s] = mn;

            float rs = 0.f;
            const int prow = pbase + (s * 16 + ln) * 72;
#pragma unroll
            for (int mt = 0; mt < 4; ++mt) {
                const float p0 = EXP2(st[s][mt][0] - mn), p1 = EXP2(st[s][mt][1] - mn);
                const float p2 = EXP2(st[s][mt][2] - mn), p3 = EXP2(st[s][mt][3] - mn);
                rs += (p0 + p1) + (p2 + p3);
                ushort4 u; u.x = f2b(p0); u.y = f2b(p1); u.z = f2b(p2); u.w = f2b(p3);
                *(ushort4*)&Ps[prow + mt * 16 + quad * 4] = u;
            }
            rs += __shfl_xor(rs, 16);
            rs += __shfl_xor(rs, 32);
            lrun[s] = lrun[s] * al + rs;

            // alpha-rescale O^T: cols are q = ln -> pure per-lane multiply
#pragma unroll
            for (int nt = 0; nt < 4; ++nt)
#pragma unroll
                for (int rg = 0; rg < 4; ++rg) ot[s][nt][rg] *= al;
        }

        // ---- O^T += V^T P^T (A-frags from Vt LDS, shared by strips)
#pragma unroll
        for (int ks = 0; ks < 2; ++ks) {
            const int kminh = kt * 64 + ks * 32;
            if (diag && kminh > q0 + 31) continue;           // both strips done
            const bool use0 = !diag || (kminh <= q0 + 15);   // strip0 live?
            const short8 pa1 = *(const short8*)&Ps[pbase + (16 + ln) * 72 + ks * 32 + quad * 8];
            short8 pa0;
            if (use0) pa0 = *(const short8*)&Ps[pbase + ln * 72 + ks * 32 + quad * 8];
#pragma unroll
            for (int nt = 0; nt < 4; ++nt) {
                const short8 vf = *(const short8*)&Vt[(nt * 16 + ln) * 72 + ks * 32 + quad * 8];
                if (use0)
                    ot[0][nt] = __builtin_amdgcn_mfma_f32_16x16x32_bf16(vf, pa0, ot[0][nt], 0, 0, 0);
                ot[1][nt] = __builtin_amdgcn_mfma_f32_16x16x32_bf16(vf, pa1, ot[1][nt], 0, 0, 0);
            }
        }
    }

    // ---- epilogue: normalize, transpose via own Ps strip, coalesced store
#pragma unroll
    for (int s = 0; s < 2; ++s) {
        const float linv = 1.0f / lrun[s];
        const int prow = pbase + (s * 16 + ln) * 72;
#pragma unroll
        for (int nt = 0; nt < 4; ++nt) {
            ushort4 u;
            u.x = f2b(ot[s][nt][0] * linv);
            u.y = f2b(ot[s][nt][1] * linv);
            u.z = f2b(ot[s][nt][2] * linv);
            u.w = f2b(ot[s][nt][3] * linv);
            *(ushort4*)&Ps[prow + nt * 16 + quad * 4] = u;   // T[q=ln][d]
        }
        const ushort* srow = &Ps[prow + quad * 16];
        ushort* drow = &ob[((bh * Np + q0 + s * 16 + ln) << 6) + quad * 16];
        *(uint4*)drow       = *(const uint4*)srow;
        *(uint4*)(drow + 8) = *(const uint4*)(srow + 8);
    }
}

// ---------------------------------------------------------------------------
// Kernel 3: projection GEMM, bf16 MFMA, 64(o) x 128(n) tile, BK=64.
// ---------------------------------------------------------------------------
__global__ __launch_bounds__(256)
void proj_gemm(const ushort* __restrict__ obuf, const ushort* __restrict__ pwb,
               const float* __restrict__ bias, float* __restrict__ out)
{
    __shared__ ushort As[64 * 72];    // pw [o][k]
    __shared__ ushort Bs[128 * 72];   // attn-out [n][k]

    const int t = threadIdx.x;
    const int w = t >> 6, lane = t & 63, quad = lane >> 4, ln = lane & 15;
    const int n0 = blockIdx.x * 128;
    const int o0 = blockIdx.y * 64;
    const int b  = blockIdx.z;
    const int nw = w * 32;

    f4 acc[4][2];
#pragma unroll
    for (int i = 0; i < 4; ++i)
#pragma unroll
        for (int j = 0; j < 2; ++j) acc[i][j] = (f4){0.f, 0.f, 0.f, 0.f};

    const int rr = t >> 2, cc = (t & 3) * 16;
    for (int k0 = 0; k0 < 512; k0 += 64) {
        __syncthreads();
        {   // A: 64 o-rows x 64 k; B: 128 n-rows x 64 k (one head per step)
            const ushort* sa = &pwb[(o0 + rr) * 512 + k0 + cc];
            *(uint4*)&As[rr * 72 + cc]     = *(const uint4*)sa;
            *(uint4*)&As[rr * 72 + cc + 8] = *(const uint4*)(sa + 8);
            const int head = k0 >> 6;
#pragma unroll
            for (int p = 0; p < 2; ++p) {
                const int row = rr + p * 64;
                const ushort* sb = &obuf[(((b * 8 + head) * Np + n0 + row) << 6) + cc];
                *(uint4*)&Bs[row * 72 + cc]     = *(const uint4*)sb;
                *(uint4*)&Bs[row * 72 + cc + 8] = *(const uint4*)(sb + 8);
            }
        }
        __syncthreads();
#pragma unroll
        for (int sub = 0; sub < 2; ++sub) {
            short8 af[4], bf[2];
#pragma unroll
            for (int ot = 0; ot < 4; ++ot)
                af[ot] = *(const short8*)&As[(ot * 16 + ln) * 72 + sub * 32 + quad * 8];
#pragma unroll
            for (int nt = 0; nt < 2; ++nt)
                bf[nt] = *(const short8*)&Bs[(nw + nt * 16 + ln) * 72 + sub * 32 + quad * 8];
#pragma unroll
            for (int ot = 0; ot < 4; ++ot)
#pragma unroll
                for (int nt = 0; nt < 2; ++nt)
                    acc[ot][nt] = __builtin_amdgcn_mfma_f32_16x16x32_bf16(
                        af[ot], bf[nt], acc[ot][nt], 0, 0, 0);
        }
    }

    // epilogue: direct fp32 stores, bias added
#pragma unroll
    for (int ot = 0; ot < 4; ++ot) {
#pragma unroll
        for (int rg = 0; rg < 4; ++rg) {
            const int oo = o0 + ot * 16 + quad * 4 + rg;
            const float pb = bias[oo];
            float* drow = &out[((b << 8) + oo) << 10];
#pragma unroll
            for (int nt = 0; nt < 2; ++nt)
                drow[n0 + nw + nt * 16 + ln] = acc[ot][nt][rg] + pb;
        }
    }
}

// ---------------------------------------------------------------------------
extern "C" void kernel_launch(void* const* d_in, const int* in_sizes, int n_in,
                              void* d_out, int out_size, void* d_ws, size_t ws_size,
                              hipStream_t stream)
{
    const float* x   = (const float*)d_in[0];   // [16,256,1024]
    const float* qw  = (const float*)d_in[1];   // [1536,256]
    const float* qbb = (const float*)d_in[2];   // [1536]
    const float* pw  = (const float*)d_in[3];   // [256,512]
    const float* pb  = (const float*)d_in[4];   // [256]
    float* out = (float*)d_out;                 // [16,256,1024]

    // workspace (all bf16): q/k [bh][n][64], v TRANSPOSED [bh][64][n],
    // attn-out [bh][n][64]; xb [b][n][c]; weights.
    const size_t per = (size_t)Bsz * 8 * Np * 64;
    ushort* qbuf = (ushort*)d_ws;
    ushort* kbuf = qbuf + per;
    ushort* vbuf = kbuf + per;
    ushort* obuf = vbuf + per;
    ushort* xb   = obuf + per;
    ushort* qwb  = xb + (size_t)Bsz * Np * Cin;
    ushort* pwb  = qwb + 1536 * Cin;

    cast_xw<<<dim3(16, 5, Bsz), 256, 0, stream>>>(x, qw, pw, xb, qwb, pwb);
    qkv_gemm<<<dim3(8, 12, Bsz), 256, 0, stream>>>(xb, qwb, qbb, qbuf, kbuf, vbuf);
    attn<<<dim3(128 * 16), 128, 0, stream>>>(qbuf, kbuf, vbuf, obuf);
    proj_gemm<<<dim3(8, 4, Bsz), 256, 0, stream>>>(obuf, pwb, pb, out);
}

// Round 10
// 166.434 us; speedup vs baseline: 1.1931x; 1.0110x over previous
//
#include <hip/hip_runtime.h>
#include <math.h>

// Problem constants: B=16, C_in=256, H=W=32 -> N=1024, qkv_out=1536,
// HEAD=8, dh=dv=64, V_DIM=512, OUT_CH=256.
static constexpr int Bsz = 16;
static constexpr int Np  = 1024;
static constexpr int Cin = 256;

typedef __attribute__((ext_vector_type(8))) short short8;  // 8 bf16 = 4 VGPR
typedef __attribute__((ext_vector_type(4))) float f4;      // mfma acc

// v_exp_f32 computes 2^x natively.
#if defined(__has_builtin)
#if __has_builtin(__builtin_amdgcn_exp2f)
#define EXP2(x) __builtin_amdgcn_exp2f(x)
#else
#define EXP2(x) exp2f(x)
#endif
#else
#define EXP2(x) exp2f(x)
#endif

// q pre-scale: dh^-0.5 * log2(e) (scores exit QK^T in log2 domain)
#define QSCALE 0.18033688011112f

// fp32 -> bf16 round-to-nearest-even
__device__ __forceinline__ unsigned short f2b(float f) {
    union { float fp; unsigned int u; } v; v.fp = f;
    unsigned int r = v.u + 0x7fffu + ((v.u >> 16) & 1u);
    return (unsigned short)(r >> 16);
}

// async global->LDS, 16B per lane (m97 recipe). lds ptr must be wave-uniform;
// lane i's 16B lands at l + i*16.
__device__ __forceinline__ void gl16(const ushort* g, ushort* l) {
    __builtin_amdgcn_global_load_lds(
        (const __attribute__((address_space(1))) unsigned int*)g,
        (__attribute__((address_space(3))) unsigned int*)l, 16, 0, 0);
}

// Swizzled-LDS staging of 8 rows x 128B (one wave-instruction):
// row stride 64 shorts (no pad); 16B chunk c of row r stored at phys c^(r&7).
// The swizzle is applied to the GLOBAL source address so the LDS deposit is
// lane-linear (global_load_lds constraint, m104). base rows multiple of 8.
// Frag read: &S[R*64 + ((c ^ (R&7)) << 3)] -> per quad-group 8 bank-groups
// x 2 lanes = 2-way aliasing = free (m136).
__device__ __forceinline__ void stage8(const ushort* grow0, int gstride,
                                       ushort* ldsrow0, int lane) {
    const int r8 = lane >> 3;               // 0..7 within the 8-row group
    const int cl = (lane & 7) ^ r8;         // logical chunk for this lane
    gl16(grow0 + r8 * gstride + (cl << 3), ldsrow0);
}

// ---------------------------------------------------------------------------
// Kernel 0: cast+transpose x [b][c][n] fp32 -> xb [b][n][c] bf16 (y<4),
// and cast qkv_w / proj_w fp32 -> bf16 (y==4). Single launch.
// ---------------------------------------------------------------------------
__global__ __launch_bounds__(256)
void cast_xw(const float* __restrict__ x, const float* __restrict__ qw,
             const float* __restrict__ pw, ushort* __restrict__ xb,
             ushort* __restrict__ qwb, ushort* __restrict__ pwb)
{
    const int t = threadIdx.x;
    if (blockIdx.y < 4) {
        __shared__ ushort T[64][72];   // [n][c]
        const int n0 = blockIdx.x * 64, c0 = blockIdx.y * 64, b = blockIdx.z;
        {   // read 64c x 64n, convert, transposed scatter into LDS
            const int c_l = t >> 2, ns = (t & 3) * 16;
            const float* src = &x[((b * Cin + c0 + c_l) << 10) + n0 + ns];
#pragma unroll
            for (int i = 0; i < 4; ++i) {
                const float4 v = *(const float4*)(src + 4 * i);
                T[ns + 4 * i + 0][c_l] = f2b(v.x);
                T[ns + 4 * i + 1][c_l] = f2b(v.y);
                T[ns + 4 * i + 2][c_l] = f2b(v.z);
                T[ns + 4 * i + 3][c_l] = f2b(v.w);
            }
        }
        __syncthreads();
        {   // write rows of c (contiguous) to xb
            const int n_l = t >> 2, cs = (t & 3) * 16;
            ushort* dst = &xb[((b << 10) + n0 + n_l) * Cin + c0 + cs];
            *(uint4*)dst       = *(const uint4*)&T[n_l][cs];
            *(uint4*)(dst + 8) = *(const uint4*)&T[n_l][cs + 8];
        }
    } else {
        // weights: 524288 floats = 131072 float4; 256 blocks x 256 thr x 2
        const int nq4 = (1536 * Cin) / 4;
        const int base = ((blockIdx.z * 16 + blockIdx.x) * 256 + t) * 2;
#pragma unroll
        for (int g = 0; g < 2; ++g) {
            const int j = base + g;
            const float* src; ushort* dst; int jj;
            if (j < nq4) { src = qw; dst = qwb; jj = j; }
            else         { src = pw; dst = pwb; jj = j - nq4; }
            const float4 v = *(const float4*)(src + 4 * jj);
            ushort4 u; u.x = f2b(v.x); u.y = f2b(v.y); u.z = f2b(v.z); u.w = f2b(v.w);
            *(ushort4*)(dst + 4 * jj) = u;
        }
    }
}

// ---------------------------------------------------------------------------
// Kernel 1: QKV GEMM, bf16 MFMA 16x16x32, BK=64, global_load_lds staging
// (swizzled, no VGPR round-trip, no ds_write). Q/K o-tiles: C = W*X ->
// Ct [n][o] -> q/k [bh][n][64] (q pre-scaled QSCALE). V o-tiles: swapped
// operands (C^T = X*W) -> vbuf TRANSPOSED [bh][d][n].
// ---------------------------------------------------------------------------
__global__ __launch_bounds__(256)
void qkv_gemm(const ushort* __restrict__ xb, const ushort* __restrict__ wb,
              const float* __restrict__ bias,
              ushort* __restrict__ qb, ushort* __restrict__ kb, ushort* __restrict__ vb)
{
    __shared__ ushort lds[17408];        // 34.8 KB; staging 32 KB + Ct alias
    ushort* As = lds;                    // [128 o][64] swizzled
    ushort* Bs = lds + 8192;             // [128 n][64] swizzled

    const int t = threadIdx.x;
    const int w = t >> 6, lane = t & 63, quad = lane >> 4, ln = lane & 15;
    const int n0 = blockIdx.x * 128;
    const int o0 = blockIdx.y * 128;
    const int b  = blockIdx.z;
    const int ow = (w & 1) * 64, nw = (w >> 1) * 64;
    const bool vpath = (o0 >= 1024);
    const int sw = ln & 7;               // frag-read swizzle key (row&7)

    f4 acc[4][4];
#pragma unroll
    for (int i = 0; i < 4; ++i)
#pragma unroll
        for (int j = 0; j < 4; ++j) acc[i][j] = (f4){0.f, 0.f, 0.f, 0.f};

    for (int k0 = 0; k0 < Cin; k0 += 64) {
        __syncthreads();
        // stage A and B: wave w owns rows [w*32, w*32+32) of each
#pragma unroll
        for (int g = 0; g < 4; ++g) {
            const int row = w * 32 + g * 8;
            stage8(&wb[(o0 + row) * Cin + k0], Cin, &As[row * 64], lane);
            stage8(&xb[((b << 10) + n0 + row) * Cin + k0], Cin, &Bs[row * 64], lane);
        }
        __syncthreads();
#pragma unroll
        for (int sub = 0; sub < 2; ++sub) {
            short8 af[4], bf[4];
#pragma unroll
            for (int ot = 0; ot < 4; ++ot)
                af[ot] = *(const short8*)&As[(ow + ot * 16 + ln) * 64 +
                         ((((sub << 2) + quad) ^ sw) << 3)];
#pragma unroll
            for (int nt = 0; nt < 4; ++nt)
                bf[nt] = *(const short8*)&Bs[(nw + nt * 16 + ln) * 64 +
                         ((((sub << 2) + quad) ^ sw) << 3)];
            if (!vpath) {   // acc[ot][nt]: row = o, col = n
#pragma unroll
                for (int ot = 0; ot < 4; ++ot)
#pragma unroll
                    for (int nt = 0; nt < 4; ++nt)
                        acc[ot][nt] = __builtin_amdgcn_mfma_f32_16x16x32_bf16(
                            af[ot], bf[nt], acc[ot][nt], 0, 0, 0);
            } else {        // acc[nt][ot]: row = n, col = o (transposed C)
#pragma unroll
                for (int nt = 0; nt < 4; ++nt)
#pragma unroll
                    for (int ot = 0; ot < 4; ++ot)
                        acc[nt][ot] = __builtin_amdgcn_mfma_f32_16x16x32_bf16(
                            bf[nt], af[ot], acc[nt][ot], 0, 0, 0);
            }
        }
    }

    __syncthreads();                     // staging reads done; alias lds
    if (!vpath) {
        // ---- Q/K epilogue: Ct [n][136 o-stride] ----
        ushort* Ct = lds;
        const float sc = (o0 < 512) ? QSCALE : 1.0f;
#pragma unroll
        for (int ot = 0; ot < 4; ++ot) {
            float bs[4];
#pragma unroll
            for (int rg = 0; rg < 4; ++rg)
                bs[rg] = bias[o0 + ow + ot * 16 + quad * 4 + rg];
#pragma unroll
            for (int nt = 0; nt < 4; ++nt) {
                ushort4 u;
                u.x = f2b((acc[ot][nt][0] + bs[0]) * sc);
                u.y = f2b((acc[ot][nt][1] + bs[1]) * sc);
                u.z = f2b((acc[ot][nt][2] + bs[2]) * sc);
                u.w = f2b((acc[ot][nt][3] + bs[3]) * sc);
                *(ushort4*)&Ct[(nw + nt * 16 + ln) * 136 + ow + ot * 16 + quad * 4] = u;
            }
        }
        __syncthreads();
        ushort* dst; int obase;
        if (o0 < 512) { dst = qb; obase = o0; }
        else          { dst = kb; obase = o0 - 512; }
        const int rn = t >> 1, hf = t & 1;
        const int bh = b * 8 + (obase >> 6) + hf;
        ushort* drow = &dst[(bh * Np + n0 + rn) << 6];
        const ushort* srow = &Ct[rn * 136 + hf * 64];
#pragma unroll
        for (int s = 0; s < 8; ++s)
            *(uint4*)(drow + s * 8) = *(const uint4*)(srow + s * 8);
    } else {
        // ---- V epilogue: Ct [o][136 n-stride] (rows = d), then [bh][d][n] ----
        ushort* Ct = lds;
#pragma unroll
        for (int ot = 0; ot < 4; ++ot) {
            const float bo = bias[o0 + ow + ot * 16 + ln];
#pragma unroll
            for (int nt = 0; nt < 4; ++nt) {
                ushort4 u;
                u.x = f2b(acc[nt][ot][0] + bo);
                u.y = f2b(acc[nt][ot][1] + bo);
                u.z = f2b(acc[nt][ot][2] + bo);
                u.w = f2b(acc[nt][ot][3] + bo);
                *(ushort4*)&Ct[(ow + ot * 16 + ln) * 136 + nw + nt * 16 + quad * 4] = u;
            }
        }
        __syncthreads();
        const int o_l = t >> 1, nh = (t & 1) * 64;
        const int bh = b * 8 + ((o0 - 1024) >> 6) + (o_l >> 6);
        ushort* drow = &vb[((size_t)bh << 16) + ((o_l & 63) << 10) + n0 + nh];
        const ushort* srow = &Ct[o_l * 136 + nh];
#pragma unroll
        for (int s = 0; s < 8; ++s)
            *(uint4*)(drow + s * 8) = *(const uint4*)(srow + s * 8);
    }
}

// ---------------------------------------------------------------------------
// Kernel 2: causal flash attention, bf16 MFMA. 128-thread blocks (2 waves),
// block covers 64 q-rows, wave owns 32 (2 strips of 16). Unchanged from R9.
// ---------------------------------------------------------------------------
__global__ __launch_bounds__(128)
void attn(const ushort* __restrict__ qb, const ushort* __restrict__ kb,
          const ushort* __restrict__ vt, ushort* __restrict__ ob)
{
    __shared__ ushort Ks[64 * 72];    // [k][d]
    __shared__ ushort Vt[64 * 72];    // [d][k]
    __shared__ ushort Ps[64 * 72];    // [q][k], 32 rows per wave

    const int t = threadIdx.x;
    const int w = t >> 6, lane = t & 63, quad = lane >> 4, ln = lane & 15;
    const int bh = blockIdx.x & 127;
    const int qt = 15 - (blockIdx.x >> 7);   // heavy q-blocks first
    const int q0 = qt * 64 + w * 32;         // this wave's 32 q-rows
    const int pbase = (w * 32) * 72;

    short8 qa[2][2];
#pragma unroll
    for (int s = 0; s < 2; ++s)
#pragma unroll
        for (int h = 0; h < 2; ++h)
            qa[s][h] = *(const short8*)&qb[((bh * Np + q0 + s * 16 + ln) << 6) + h * 32 + quad * 8];

    f4 ot[2][4];
#pragma unroll
    for (int s = 0; s < 2; ++s)
#pragma unroll
        for (int nt = 0; nt < 4; ++nt) ot[s][nt] = (f4){0.f, 0.f, 0.f, 0.f};
    float mrun[2] = {-INFINITY, -INFINITY}, lrun[2] = {0.f, 0.f};

    const int rr = t >> 1, cc = (t & 1) * 32;
    for (int kt = 0; kt <= qt; ++kt) {
        __syncthreads();
        {   // stage K [k][d] and Vt [d][k]
            const ushort* sk = &kb[((bh * Np + kt * 64 + rr) << 6) + cc];
            *(uint4*)&Ks[rr * 72 + cc]     = *(const uint4*)sk;
            *(uint4*)&Ks[rr * 72 + cc + 8] = *(const uint4*)(sk + 8);
            *(uint4*)&Ks[rr * 72 + cc + 16] = *(const uint4*)(sk + 16);
            *(uint4*)&Ks[rr * 72 + cc + 24] = *(const uint4*)(sk + 24);
            const ushort* sv = &vt[((size_t)bh << 16) + (rr << 10) + kt * 64 + cc];
            *(uint4*)&Vt[rr * 72 + cc]     = *(const uint4*)sv;
            *(uint4*)&Vt[rr * 72 + cc + 8] = *(const uint4*)(sv + 8);
            *(uint4*)&Vt[rr * 72 + cc + 16] = *(const uint4*)(sv + 16);
            *(uint4*)&Vt[rr * 72 + cc + 24] = *(const uint4*)(sv + 24);
        }
        __syncthreads();
        const bool diag = (kt == qt);

        f4 st[2][4];
#pragma unroll
        for (int mt = 0; mt < 4; ++mt) {
            const int kmin = kt * 64 + mt * 16;
            if (diag && kmin > q0 + 31) {
                st[0][mt] = (f4){-INFINITY, -INFINITY, -INFINITY, -INFINITY};
                st[1][mt] = st[0][mt];
                continue;
            }
            const short8 ka0 = *(const short8*)&Ks[(mt * 16 + ln) * 72 + quad * 8];
            const short8 ka1 = *(const short8*)&Ks[(mt * 16 + ln) * 72 + 32 + quad * 8];
#pragma unroll
            for (int s = 0; s < 2; ++s) {
                if (diag && kmin > q0 + s * 16 + 15) {
                    st[s][mt] = (f4){-INFINITY, -INFINITY, -INFINITY, -INFINITY};
                } else {
                    f4 z = (f4){0.f, 0.f, 0.f, 0.f};
                    z = __builtin_amdgcn_mfma_f32_16x16x32_bf16(ka0, qa[s][0], z, 0, 0, 0);
                    st[s][mt] = __builtin_amdgcn_mfma_f32_16x16x32_bf16(ka1, qa[s][1], z, 0, 0, 0);
                }
            }
        }

        if (diag) {
#pragma unroll
            for (int s = 0; s < 2; ++s) {
                const int q = q0 + s * 16 + ln;
#pragma unroll
                for (int mt = 0; mt < 4; ++mt) {
                    const int kb_ = kt * 64 + mt * 16 + quad * 4;
#pragma unroll
                    for (int rg = 0; rg < 4; ++rg)
                        if (kb_ + rg > q) st[s][mt][rg] = -INFINITY;
                }
            }
        }

#pragma unroll
        for (int s = 0; s < 2; ++s) {
            float mx = -INFINITY;
#pragma unroll
            for (int mt = 0; mt < 4; ++mt)
#pragma unroll
                for (int rg = 0; rg < 4; ++rg) mx = fmaxf(mx, st[s][mt][rg]);
            mx = fmaxf(mx, __shfl_xor(mx, 16));
            mx = fmaxf(mx, __shfl_xor(mx, 32));

            const float mn = fmaxf(mrun[s], mx);
            const float al = EXP2(mrun[s] - mn);
            mrun[s] = mn;

            float rs = 0.f;
            const int prow = pbase + (s * 16 + ln) * 72;
#pragma unroll
            for (int mt = 0; mt < 4; ++mt) {
                const float p0 = EXP2(st[s][mt][0] - mn), p1 = EXP2(st[s][mt][1] - mn);
                const float p2 = EXP2(st[s][mt][2] - mn), p3 = EXP2(st[s][mt][3] - mn);
                rs += (p0 + p1) + (p2 + p3);
                ushort4 u; u.x = f2b(p0); u.y = f2b(p1); u.z = f2b(p2); u.w = f2b(p3);
                *(ushort4*)&Ps[prow + mt * 16 + quad * 4] = u;
            }
            rs += __shfl_xor(rs, 16);
            rs += __shfl_xor(rs, 32);
            lrun[s] = lrun[s] * al + rs;

#pragma unroll
            for (int nt = 0; nt < 4; ++nt)
#pragma unroll
                for (int rg = 0; rg < 4; ++rg) ot[s][nt][rg] *= al;
        }

#pragma unroll
        for (int ks = 0; ks < 2; ++ks) {
            const int kminh = kt * 64 + ks * 32;
            if (diag && kminh > q0 + 31) continue;
            const bool use0 = !diag || (kminh <= q0 + 15);
            const short8 pa1 = *(const short8*)&Ps[pbase + (16 + ln) * 72 + ks * 32 + quad * 8];
            short8 pa0;
            if (use0) pa0 = *(const short8*)&Ps[pbase + ln * 72 + ks * 32 + quad * 8];
#pragma unroll
            for (int nt = 0; nt < 4; ++nt) {
                const short8 vf = *(const short8*)&Vt[(nt * 16 + ln) * 72 + ks * 32 + quad * 8];
                if (use0)
                    ot[0][nt] = __builtin_amdgcn_mfma_f32_16x16x32_bf16(vf, pa0, ot[0][nt], 0, 0, 0);
                ot[1][nt] = __builtin_amdgcn_mfma_f32_16x16x32_bf16(vf, pa1, ot[1][nt], 0, 0, 0);
            }
        }
    }

    // ---- epilogue: normalize, transpose via own Ps strip, coalesced store
#pragma unroll
    for (int s = 0; s < 2; ++s) {
        const float linv = 1.0f / lrun[s];
        const int prow = pbase + (s * 16 + ln) * 72;
#pragma unroll
        for (int nt = 0; nt < 4; ++nt) {
            ushort4 u;
            u.x = f2b(ot[s][nt][0] * linv);
            u.y = f2b(ot[s][nt][1] * linv);
            u.z = f2b(ot[s][nt][2] * linv);
            u.w = f2b(ot[s][nt][3] * linv);
            *(ushort4*)&Ps[prow + nt * 16 + quad * 4] = u;   // T[q=ln][d]
        }
        const ushort* srow = &Ps[prow + quad * 16];
        ushort* drow = &ob[((bh * Np + q0 + s * 16 + ln) << 6) + quad * 16];
        *(uint4*)drow       = *(const uint4*)srow;
        *(uint4*)(drow + 8) = *(const uint4*)(srow + 8);
    }
}

// ---------------------------------------------------------------------------
// Kernel 3: projection GEMM, bf16 MFMA, 64(o) x 128(n) tile, BK=64,
// global_load_lds staging (swizzled). LDS 24.6 KB.
// ---------------------------------------------------------------------------
__global__ __launch_bounds__(256)
void proj_gemm(const ushort* __restrict__ obuf, const ushort* __restrict__ pwb,
               const float* __restrict__ bias, float* __restrict__ out)
{
    __shared__ ushort As[64 * 64];    // pw [o][k] swizzled
    __shared__ ushort Bs[128 * 64];   // attn-out [n][k] swizzled

    const int t = threadIdx.x;
    const int w = t >> 6, lane = t & 63, quad = lane >> 4, ln = lane & 15;
    const int n0 = blockIdx.x * 128;
    const int o0 = blockIdx.y * 64;
    const int b  = blockIdx.z;
    const int nw = w * 32;
    const int sw = ln & 7;

    f4 acc[4][2];
#pragma unroll
    for (int i = 0; i < 4; ++i)
#pragma unroll
        for (int j = 0; j < 2; ++j) acc[i][j] = (f4){0.f, 0.f, 0.f, 0.f};

    for (int k0 = 0; k0 < 512; k0 += 64) {
        __syncthreads();
        {   // A: wave w rows [w*16,+16); B: wave w rows [w*32,+32)
            const int head = k0 >> 6;
#pragma unroll
            for (int g = 0; g < 2; ++g) {
                const int row = w * 16 + g * 8;
                stage8(&pwb[(o0 + row) * 512 + k0], 512, &As[row * 64], lane);
            }
#pragma unroll
            for (int g = 0; g < 4; ++g) {
                const int row = w * 32 + g * 8;
                stage8(&obuf[(((b * 8 + head) * Np + n0 + row) << 6)], 64,
                       &Bs[row * 64], lane);
            }
        }
        __syncthreads();
#pragma unroll
        for (int sub = 0; sub < 2; ++sub) {
            short8 af[4], bf[2];
#pragma unroll
            for (int ot = 0; ot < 4; ++ot)
                af[ot] = *(const short8*)&As[(ot * 16 + ln) * 64 +
                         ((((sub << 2) + quad) ^ sw) << 3)];
#pragma unroll
            for (int nt = 0; nt < 2; ++nt)
                bf[nt] = *(const short8*)&Bs[(nw + nt * 16 + ln) * 64 +
                         ((((sub << 2) + quad) ^ sw) << 3)];
#pragma unroll
            for (int ot = 0; ot < 4; ++ot)
#pragma unroll
                for (int nt = 0; nt < 2; ++nt)
                    acc[ot][nt] = __builtin_amdgcn_mfma_f32_16x16x32_bf16(
                        af[ot], bf[nt], acc[ot][nt], 0, 0, 0);
        }
    }

    // epilogue: direct fp32 stores, bias added
#pragma unroll
    for (int ot = 0; ot < 4; ++ot) {
#pragma unroll
        for (int rg = 0; rg < 4; ++rg) {
            const int oo = o0 + ot * 16 + quad * 4 + rg;
            const float pb = bias[oo];
            float* drow = &out[((b << 8) + oo) << 10];
#pragma unroll
            for (int nt = 0; nt < 2; ++nt)
                drow[n0 + nw + nt * 16 + ln] = acc[ot][nt][rg] + pb;
        }
    }
}

// ---------------------------------------------------------------------------
extern "C" void kernel_launch(void* const* d_in, const int* in_sizes, int n_in,
                              void* d_out, int out_size, void* d_ws, size_t ws_size,
                              hipStream_t stream)
{
    const float* x   = (const float*)d_in[0];   // [16,256,1024]
    const float* qw  = (const float*)d_in[1];   // [1536,256]
    const float* qbb = (const float*)d_in[2];   // [1536]
    const float* pw  = (const float*)d_in[3];   // [256,512]
    const float* pb  = (const float*)d_in[4];   // [256]
    float* out = (float*)d_out;                 // [16,256,1024]

    // workspace (all bf16): q/k [bh][n][64], v TRANSPOSED [bh][64][n],
    // attn-out [bh][n][64]; xb [b][n][c]; weights.
    const size_t per = (size_t)Bsz * 8 * Np * 64;
    ushort* qbuf = (ushort*)d_ws;
    ushort* kbuf = qbuf + per;
    ushort* vbuf = kbuf + per;
    ushort* obuf = vbuf + per;
    ushort* xb   = obuf + per;
    ushort* qwb  = xb + (size_t)Bsz * Np * Cin;
    ushort* pwb  = qwb + 1536 * Cin;

    cast_xw<<<dim3(16, 5, Bsz), 256, 0, stream>>>(x, qw, pw, xb, qwb, pwb);
    qkv_gemm<<<dim3(8, 12, Bsz), 256, 0, stream>>>(xb, qwb, qbb, qbuf, kbuf, vbuf);
    attn<<<dim3(128 * 16), 128, 0, stream>>>(qbuf, kbuf, vbuf, obuf);
    proj_gemm<<<dim3(8, 4, Bsz), 256, 0, stream>>>(obuf, pwb, pb, out);
}